// Round 11
// baseline (219.902 us; speedup 1.0000x reference)
//
#include <hip/hip_runtime.h>
#include <hip/hip_cooperative_groups.h>

namespace cg = cooperative_groups;

typedef __attribute__((ext_vector_type(8))) short bf16x8;
typedef __attribute__((ext_vector_type(4))) float f32x4;
typedef __attribute__((ext_vector_type(4))) _Float16 h16x4;
typedef unsigned short u16;
typedef unsigned int u32;

__device__ __forceinline__ u16 f2bf(float f) {
    u32 x = __builtin_bit_cast(u32, f);
    return (u16)((x + 0x7fffu + ((x >> 16) & 1u)) >> 16);
}
__device__ __forceinline__ u16 f2h(float f) {
    _Float16 h = (_Float16)f;
    return __builtin_bit_cast(u16, h);
}
__device__ __forceinline__ float h2f(u16 u) {
    return (float)__builtin_bit_cast(_Float16, u);
}

// ---------------------------------------------------------------------------
// Single cooperative kernel: 256 blocks x 512 threads (1 block/CU guaranteed).
//  Phase A: y = relu(BN(w1 @ x))            (64n-tile per block)
//  Phase B: wt = w2g @ y + b2 ; involution  (4 items per block)
//  Phase C: out = wp @ inv                  (2 x 64m x 128n tiles per block)
// ---------------------------------------------------------------------------
__global__ __launch_bounds__(512, 2) void fused_all_k(
    const float* __restrict__ x,  const float* __restrict__ w1,
    const float* __restrict__ gamma, const float* __restrict__ beta,
    const float* __restrict__ mean,  const float* __restrict__ var,
    const float* __restrict__ w2, const float* __restrict__ b2,
    const float* __restrict__ wp, float* __restrict__ out,
    u16* __restrict__ ypk, u16* __restrict__ invpk)
{
    __shared__ alignas(16) char Lds[66560];
    cg::grid_group grid = cg::this_grid();

    const int t = threadIdx.x, blk = blockIdx.x;
    const int lane = t & 63, wave = t >> 6;
    const int ln = lane & 15, lk = lane >> 4;

    // ======================= Phase A: gemm1 (round-8 body) =======================
    {
        u16* Ws = (u16*)Lds;               // [32kg][64m swz][8], 32 KB
        u16* As = (u16*)(Lds + 32768);     // [2][8kg][64n swz][8], 2 x 8 KB

        const int wm = wave >> 1, wn = wave & 1;
        const int b = blk >> 6, n0 = (blk & 63) * 64;
        const float* xb = x + (size_t)b * 256 * 4096;

        for (int s = t; s < 2048; s += 512) {
            int kg = s >> 6, m = s & 63;
            float sc = gamma[m] * rsqrtf(var[m] + 1e-5f);
            const float4 f0 = *reinterpret_cast<const float4*>(&w1[(size_t)m * 256 + kg * 8]);
            const float4 f1 = *reinterpret_cast<const float4*>(&w1[(size_t)m * 256 + kg * 8 + 4]);
            uint4 v;
            v.x = (u32)f2bf(f0.x * sc) | ((u32)f2bf(f0.y * sc) << 16);
            v.y = (u32)f2bf(f0.z * sc) | ((u32)f2bf(f0.w * sc) << 16);
            v.z = (u32)f2bf(f1.x * sc) | ((u32)f2bf(f1.y * sc) << 16);
            v.w = (u32)f2bf(f1.z * sc) | ((u32)f2bf(f1.w * sc) << 16);
            *reinterpret_cast<uint4*>(&Ws[((kg * 64) + (m ^ (kg & 7))) * 8]) = v;
        }

        const int skg = t >> 6, snn = t & 63;
        float rx[8];
#pragma unroll
        for (int j = 0; j < 8; ++j)
            rx[j] = xb[(size_t)(skg * 8 + j) * 4096 + n0 + snn];
        {
            uint4 v;
            v.x = (u32)f2bf(rx[0]) | ((u32)f2bf(rx[1]) << 16);
            v.y = (u32)f2bf(rx[2]) | ((u32)f2bf(rx[3]) << 16);
            v.z = (u32)f2bf(rx[4]) | ((u32)f2bf(rx[5]) << 16);
            v.w = (u32)f2bf(rx[6]) | ((u32)f2bf(rx[7]) << 16);
            *reinterpret_cast<uint4*>(&As[((skg * 64) + (snn ^ skg)) * 8]) = v;
        }
        __syncthreads();

        f32x4 acc[2];
#pragma unroll
        for (int i = 0; i < 2; ++i)
#pragma unroll
            for (int e = 0; e < 4; ++e) acc[i][e] = 0.f;

        for (int ks = 0; ks < 4; ++ks) {
            const int cur = ks & 1;
            if (ks < 3) {
#pragma unroll
                for (int j = 0; j < 8; ++j)
                    rx[j] = xb[(size_t)((ks + 1) * 64 + skg * 8 + j) * 4096 + n0 + snn];
            }
#pragma unroll
            for (int k32 = 0; k32 < 2; ++k32) {
                const int kgl = k32 * 4 + lk;
                const int kgw = ks * 8 + kgl;
                const bf16x8 aw = *reinterpret_cast<const bf16x8*>(
                    &Ws[((kgw * 64) + ((wm * 16 + ln) ^ (kgw & 7))) * 8]);
#pragma unroll
                for (int i = 0; i < 2; ++i) {
                    const int n = wn * 32 + i * 16 + ln;
                    const bf16x8 bx = *reinterpret_cast<const bf16x8*>(
                        &As[(cur * 4096) + ((kgl * 64) + (n ^ kgl)) * 8]);
                    acc[i] = __builtin_amdgcn_mfma_f32_16x16x32_bf16(aw, bx, acc[i], 0, 0, 0);
                }
            }
            if (ks < 3) {
                uint4 v;
                v.x = (u32)f2bf(rx[0]) | ((u32)f2bf(rx[1]) << 16);
                v.y = (u32)f2bf(rx[2]) | ((u32)f2bf(rx[3]) << 16);
                v.z = (u32)f2bf(rx[4]) | ((u32)f2bf(rx[5]) << 16);
                v.w = (u32)f2bf(rx[6]) | ((u32)f2bf(rx[7]) << 16);
                *reinterpret_cast<uint4*>(
                    &As[((cur ^ 1) * 4096) + ((skg * 64) + (snn ^ skg)) * 8]) = v;
                __syncthreads();
            }
        }

        const int mb = wm * 16 + lk * 4;
        const float4 g4 = *reinterpret_cast<const float4*>(&gamma[mb]);
        const float4 v4 = *reinterpret_cast<const float4*>(&var[mb]);
        const float4 be4 = *reinterpret_cast<const float4*>(&beta[mb]);
        const float4 mn4 = *reinterpret_cast<const float4*>(&mean[mb]);
        float bv[4];
        bv[0] = be4.x - mn4.x * (g4.x * rsqrtf(v4.x + 1e-5f));
        bv[1] = be4.y - mn4.y * (g4.y * rsqrtf(v4.y + 1e-5f));
        bv[2] = be4.z - mn4.z * (g4.z * rsqrtf(v4.z + 1e-5f));
        bv[3] = be4.w - mn4.w * (g4.w * rsqrtf(v4.w + 1e-5f));
        const int kg = mb >> 3, joff = mb & 7;
#pragma unroll
        for (int i = 0; i < 2; ++i) {
            const int n = n0 + wn * 32 + i * 16 + ln;
            u16 p[4];
#pragma unroll
            for (int r = 0; r < 4; ++r)
                p[r] = f2bf(fmaxf(acc[i][r] + bv[r], 0.f));
            uint2 v;
            v.x = (u32)p[0] | ((u32)p[1] << 16);
            v.y = (u32)p[2] | ((u32)p[3] << 16);
            *reinterpret_cast<uint2*>(
                &ypk[(((size_t)b * 8 + kg) * 4096 + n) * 8 + joff]) = v;
        }
    }

    __threadfence();
    grid.sync();

    // ======================= Phase B: fusedinv (4 items) =======================
    for (int rep = 0; rep < 4; ++rep) {
        __syncthreads();
        const int id = blk * 4 + rep;
        const int b = id >> 8, g = (id >> 4) & 15, tile = id & 15;
        const int ty0 = (tile >> 2) * 16, tx0 = (tile & 3) * 16;

        u16* As = (u16*)Lds;                   // [8kg][256px swz][8], 32 KB
        u16* Ws = (u16*)(Lds + 32768);         // [8kg][64kk swz][8], 8 KB
        u16* wt16 = (u16*)(Lds + 40960);       // [49][260] f16, 25.5 KB
        const int q = wave >> 1, hh_ = wave & 1;

        const u16* yb = ypk + (size_t)b * 8 * 4096 * 8;
#pragma unroll
        for (int r = 0; r < 4; ++r) {
            int s = r * 512 + t;
            int kg = s >> 8, n = s & 255;
            int gpix = (ty0 + (n >> 4)) * 64 + tx0 + (n & 15);
            *reinterpret_cast<uint4*>(&As[((kg * 256) + (n ^ kg)) * 8]) =
                *reinterpret_cast<const uint4*>(&yb[((size_t)kg * 4096 + gpix) * 8]);
        }
        {
            int kg = t >> 6, m = t & 63;
            uint4 v = {0u, 0u, 0u, 0u};
            if (m < 49) {
                const float4 f0 = *reinterpret_cast<const float4*>(
                    &w2[(size_t)(g * 49 + m) * 64 + kg * 8]);
                const float4 f1 = *reinterpret_cast<const float4*>(
                    &w2[(size_t)(g * 49 + m) * 64 + kg * 8 + 4]);
                v.x = (u32)f2bf(f0.x) | ((u32)f2bf(f0.y) << 16);
                v.y = (u32)f2bf(f0.z) | ((u32)f2bf(f0.w) << 16);
                v.z = (u32)f2bf(f1.x) | ((u32)f2bf(f1.y) << 16);
                v.w = (u32)f2bf(f1.z) | ((u32)f2bf(f1.w) << 16);
            }
            *reinterpret_cast<uint4*>(&Ws[((kg * 64) + (m ^ kg)) * 8]) = v;
        }
        __syncthreads();

        f32x4 acc[8];
#pragma unroll
        for (int i = 0; i < 8; ++i)
#pragma unroll
            for (int e = 0; e < 4; ++e) acc[i][e] = 0.f;

#pragma unroll
        for (int k32 = 0; k32 < 2; ++k32) {
            const int kg = k32 * 4 + lk;
            const bf16x8 wf = *reinterpret_cast<const bf16x8*>(
                &Ws[((kg * 64) + ((q * 16 + ln) ^ kg)) * 8]);
#pragma unroll
            for (int i = 0; i < 8; ++i) {
                const int n = (hh_ * 8 + i) * 16 + ln;
                const bf16x8 af = *reinterpret_cast<const bf16x8*>(
                    &As[((kg * 256) + (n ^ kg)) * 8]);
                acc[i] = __builtin_amdgcn_mfma_f32_16x16x32_bf16(af, wf, acc[i], 0, 0, 0);
            }
        }
        __syncthreads();

        const int kk0 = q * 16 + ln;
        if (kk0 < 49) {
            const float bv = b2[g * 49 + kk0];
#pragma unroll
            for (int i = 0; i < 8; ++i) {
                u16 h0 = f2h(acc[i][0] + bv), h1 = f2h(acc[i][1] + bv);
                u16 h2 = f2h(acc[i][2] + bv), h3 = f2h(acc[i][3] + bv);
                uint2 v;
                v.x = (u32)h0 | ((u32)h1 << 16);
                v.y = (u32)h2 | ((u32)h3 << 16);
                *reinterpret_cast<uint2*>(&wt16[kk0 * 260 + (hh_ * 8 + i) * 16 + lk * 4]) = v;
            }
        }

        // x patch staging: fp32 -> f16, XOR-swizzled b64s
        const float* xb = x + (size_t)(b * 256 + g * 16) * 4096;
        for (int idx = t; idx < 968; idx += 512) {
            int plane = idx / 484, sp = idx - plane * 484;
            int sy = sp / 22, sx = sp - sy * 22;
            int gy = ty0 + sy - 3, gx = tx0 + sx - 3;
            uint4 hh = {0u, 0u, 0u, 0u};
            if ((unsigned)gy < 64u && (unsigned)gx < 64u) {
                const float* xp = &xb[(size_t)(plane * 8) * 4096 + gy * 64 + gx];
                float f[8];
#pragma unroll
                for (int j = 0; j < 8; ++j) f[j] = xp[(size_t)j * 4096];
                hh.x = (u32)f2h(f[0]) | ((u32)f2h(f[1]) << 16);
                hh.y = (u32)f2h(f[2]) | ((u32)f2h(f[3]) << 16);
                hh.z = (u32)f2h(f[4]) | ((u32)f2h(f[5]) << 16);
                hh.w = (u32)f2h(f[6]) | ((u32)f2h(f[7]) << 16);
            }
            const size_t base = (size_t)(plane * 484 + sp) * 16;
            const size_t key = (size_t)((sy & 7) << 3);
            *reinterpret_cast<uint2*>((size_t)(Lds) + (base ^ key)) = uint2{hh.x, hh.y};
            *reinterpret_cast<uint2*>((size_t)(Lds) + ((base + 8) ^ key)) = uint2{hh.z, hh.w};
        }
        __syncthreads();

        // involution; thread = (px-pair, plane, ch-quad)
        const int pp = t & 127, qq = t >> 7;
        const int plane = qq >> 1, cq = qq & 1;
        const int px0 = pp * 2;
        const int py = px0 >> 4, pxx = px0 & 15;

        float o0[4] = {0.f, 0.f, 0.f, 0.f};
        float o1[4] = {0.f, 0.f, 0.f, 0.f};

        for (int dy = 0; dy < 7; ++dy) {
            const int sy = py + dy;
            const size_t rowbase = ((size_t)(plane * 484 + sy * 22 + pxx) * 16) + cq * 8;
            const size_t key = (size_t)((sy & 7) << 3);
            h16x4 xv[8];
#pragma unroll
            for (int r = 0; r < 8; ++r) {
                uint2 u = *reinterpret_cast<const uint2*>(
                    (size_t)(Lds) + ((rowbase + (size_t)r * 16) ^ key));
                xv[r] = __builtin_bit_cast(h16x4, u);
            }
#pragma unroll
            for (int dx = 0; dx < 7; ++dx) {
                const int kk = dy * 7 + dx;
                const u32 wpair = *reinterpret_cast<const u32*>(&wt16[kk * 260 + px0]);
                const float w0 = h2f((u16)(wpair & 0xffffu));
                const float w1v = h2f((u16)(wpair >> 16));
#pragma unroll
                for (int c = 0; c < 4; ++c) {
                    o0[c] += w0 * (float)xv[dx][c];
                    o1[c] += w1v * (float)xv[dx + 1][c];
                }
            }
        }

        const int pix = (ty0 + py) * 64 + tx0 + pxx;
        u16* ob = invpk + (((size_t)b * 32 + g * 2 + plane) * 4096 + pix) * 8 + cq * 4;
        {
            uint2 v;
            v.x = (u32)f2bf(o0[0]) | ((u32)f2bf(o0[1]) << 16);
            v.y = (u32)f2bf(o0[2]) | ((u32)f2bf(o0[3]) << 16);
            *reinterpret_cast<uint2*>(ob) = v;
            uint2 w;
            w.x = (u32)f2bf(o1[0]) | ((u32)f2bf(o1[1]) << 16);
            w.y = (u32)f2bf(o1[2]) | ((u32)f2bf(o1[3]) << 16);
            *reinterpret_cast<uint2*>(ob + 8) = w;
        }
    }

    __threadfence();
    grid.sync();

    // ======================= Phase C: final GEMM (2 sub-tiles) =======================
    for (int sub = 0; sub < 2; ++sub) {
        __syncthreads();
        const int sid = blk * 2 + sub;          // 0..511
        u16* Asb = (u16*)Lds;                   // [2][8kg][128n swz][8], 2 x 16 KB
        u16* Ws = (u16*)(Lds + 32768);          // [32kg][64m swz][8], 32 KB

        const int m0 = (sid >> 7) * 64;
        const int yi = sid & 127;
        const int batch = yi >> 5;
        const int n0 = (yi & 31) * 128;
        const u16* Ab = invpk + (size_t)batch * 32 * 4096 * 8;

        const int wn = wave & 3, wm = wave >> 2;

        for (int s = t; s < 2048; s += 512) {
            int kg = s >> 6, m = s & 63;
            const float4 f0 = *reinterpret_cast<const float4*>(
                &wp[(size_t)(m0 + m) * 256 + kg * 8]);
            const float4 f1 = *reinterpret_cast<const float4*>(
                &wp[(size_t)(m0 + m) * 256 + kg * 8 + 4]);
            uint4 v;
            v.x = (u32)f2bf(f0.x) | ((u32)f2bf(f0.y) << 16);
            v.y = (u32)f2bf(f0.z) | ((u32)f2bf(f0.w) << 16);
            v.z = (u32)f2bf(f1.x) | ((u32)f2bf(f1.y) << 16);
            v.w = (u32)f2bf(f1.z) | ((u32)f2bf(f1.w) << 16);
            *reinterpret_cast<uint4*>(&Ws[((size_t)kg * 64 + (m ^ (kg & 7))) * 8]) = v;
        }

        uint4 rs[2];
#pragma unroll
        for (int r = 0; r < 2; ++r) {
            int s = r * 512 + t, kg = s >> 7, nn = s & 127;
            rs[r] = *reinterpret_cast<const uint4*>(&Ab[((size_t)kg * 4096 + n0 + nn) * 8]);
        }
#pragma unroll
        for (int r = 0; r < 2; ++r) {
            int s = r * 512 + t, kg = s >> 7, nn = s & 127;
            *reinterpret_cast<uint4*>(&Asb[((size_t)kg * 128 + (nn ^ kg)) * 8]) = rs[r];
        }
        __syncthreads();

        f32x4 acc[2][2];
#pragma unroll
        for (int i = 0; i < 2; ++i)
#pragma unroll
            for (int f = 0; f < 2; ++f)
#pragma unroll
                for (int e = 0; e < 4; ++e) acc[i][f][e] = 0.f;

        for (int ks = 0; ks < 4; ++ks) {
            const int cur = ks & 1;
            if (ks < 3) {
#pragma unroll
                for (int r = 0; r < 2; ++r) {
                    int s = r * 512 + t, kg = s >> 7, nn = s & 127;
                    rs[r] = *reinterpret_cast<const uint4*>(
                        &Ab[(((size_t)(ks + 1) * 8 + kg) * 4096 + n0 + nn) * 8]);
                }
            }
#pragma unroll
            for (int k32 = 0; k32 < 2; ++k32) {
                const int kg = k32 * 4 + lk;
                const int kgw = ks * 8 + kg;
                bf16x8 a[2], bfr[2];
#pragma unroll
                for (int i = 0; i < 2; ++i) {
                    int n = wn * 32 + i * 16 + ln;
                    a[i] = *reinterpret_cast<const bf16x8*>(
                        &Asb[(cur * 1024 + (size_t)kg * 128 + (n ^ kg)) * 8]);
                }
#pragma unroll
                for (int f = 0; f < 2; ++f) {
                    int m = wm * 32 + f * 16 + ln;
                    bfr[f] = *reinterpret_cast<const bf16x8*>(
                        &Ws[((size_t)kgw * 64 + (m ^ (kgw & 7))) * 8]);
                }
#pragma unroll
                for (int i = 0; i < 2; ++i)
#pragma unroll
                    for (int f = 0; f < 2; ++f)
                        acc[i][f] = __builtin_amdgcn_mfma_f32_16x16x32_bf16(
                            a[i], bfr[f], acc[i][f], 0, 0, 0);
            }
            if (ks < 3) {
#pragma unroll
                for (int r = 0; r < 2; ++r) {
                    int s = r * 512 + t, kg = s >> 7, nn = s & 127;
                    *reinterpret_cast<uint4*>(
                        &Asb[((cur ^ 1) * 1024 + (size_t)kg * 128 + (nn ^ kg)) * 8]) = rs[r];
                }
                __syncthreads();
            }
        }

#pragma unroll
        for (int f = 0; f < 2; ++f) {
            const int m = m0 + wm * 32 + f * 16 + ln;
#pragma unroll
            for (int i = 0; i < 2; ++i) {
                const int n = n0 + wn * 32 + i * 16 + lk * 4;
                float4 v = {acc[i][f][0], acc[i][f][1], acc[i][f][2], acc[i][f][3]};
                *reinterpret_cast<float4*>(&out[((size_t)batch * 256 + m) * 4096 + n]) = v;
            }
        }
    }
}

// ---------------------------------------------------------------------------
extern "C" void kernel_launch(void* const* d_in, const int* in_sizes, int n_in,
                              void* d_out, int out_size, void* d_ws, size_t ws_size,
                              hipStream_t stream)
{
    const float* x     = (const float*)d_in[0];
    const float* w1    = (const float*)d_in[1];
    const float* gamma = (const float*)d_in[2];
    const float* beta  = (const float*)d_in[3];
    const float* mean  = (const float*)d_in[4];
    const float* var   = (const float*)d_in[5];
    const float* w2    = (const float*)d_in[6];
    const float* b2    = (const float*)d_in[7];
    const float* wp    = (const float*)d_in[8];
    float* out = (float*)d_out;

    u16* ypk   = (u16*)d_ws;            // 4*8*4096*8  = 1,048,576 u16
    u16* invpk = ypk + 1048576;         // 4*32*4096*8 = 4,194,304 u16

    void* args[] = { (void*)&x, (void*)&w1, (void*)&gamma, (void*)&beta,
                     (void*)&mean, (void*)&var, (void*)&w2, (void*)&b2,
                     (void*)&wp, (void*)&out, (void*)&ypk, (void*)&invpk };
    hipLaunchCooperativeKernel((const void*)fused_all_k, dim3(256), dim3(512),
                               args, 0, stream);
}

// Round 12
// 70.042 us; speedup vs baseline: 3.1396x; 3.1396x over previous
//
#include <hip/hip_runtime.h>

typedef __attribute__((ext_vector_type(8))) short bf16x8;
typedef __attribute__((ext_vector_type(4))) float f32x4;
typedef unsigned short u16;
typedef unsigned int u32;

__device__ __forceinline__ u16 f2bf(float f) {
    u32 x = __builtin_bit_cast(u32, f);
    return (u16)((x + 0x7fffu + ((x >> 16) & 1u)) >> 16);
}
__device__ __forceinline__ float bf2f(u16 u) {
    u32 x = ((u32)u) << 16;
    return __builtin_bit_cast(float, x);
}
__device__ __forceinline__ u16 f2h(float f) {
    _Float16 h = (_Float16)f;
    return __builtin_bit_cast(u16, h);
}
__device__ __forceinline__ float h2f(u16 u) {
    return (float)__builtin_bit_cast(_Float16, u);
}
__device__ __forceinline__ u32 pk(float a, float b) {
    return (u32)f2bf(a) | ((u32)f2bf(b) << 16);
}

// ---------------------------------------------------------------------------
// LDS layout (bytes); total 161,728 <= 163,840 (160 KiB/CU, 1 block/CU)
// ---------------------------------------------------------------------------
#define XP_OFF   0u        // bf16 [196 sp][264 ch-pad]          = 103,488
#define Y_OFF    103488u   // bf16 [8 kg][64 px ^kg][8]          =   8,192
#define W2S_OFF  111680u   // bf16 [8 kg][112 kkp ^kg][8]        =  14,336
#define WT_OFF   126016u   // f16  [112 kkp][68 px-pad]          =  15,232
#define WPS_OFF  141248u   // bf16 [4 kg][256 m ^(kg<<1)][8]     =  16,384
#define INVP_OFF 157632u   // bf16 [4 kg][64 px ^(kg<<1)][8]     =   4,096
#define LDS_SZ   161728u

// ---------------------------------------------------------------------------
// Single fully-fused kernel. Block = (batch, 8x8 pixel tile); 256 blocks,
// 512 threads. No workspace, no second launch.
//  1) stage x halo patch 14x14 x 256ch -> XP (bf16, channels contiguous = k-packed)
//  2) y[64px][64m] = relu(BN(w1 @ x)) via MFMA; A-frags read from XP interior
//  3) per group-pair p (8): stage w2/wp slice; wt = y @ w2g + b2 (MFMA -> WT f16);
//     involution (VALU) -> INVP bf16; out-acc += INVP @ WPS (MFMA, K=32)
//  4) epilogue: out fp32
// ---------------------------------------------------------------------------
__global__ __launch_bounds__(512, 1) void mega_k(
    const float* __restrict__ x,  const float* __restrict__ w1,
    const float* __restrict__ gamma, const float* __restrict__ beta,
    const float* __restrict__ mean,  const float* __restrict__ var,
    const float* __restrict__ w2, const float* __restrict__ b2,
    const float* __restrict__ wp, float* __restrict__ out)
{
    extern __shared__ char Lds[];
    u16* XP   = (u16*)(Lds + XP_OFF);
    u16* Y    = (u16*)(Lds + Y_OFF);
    u16* W2S  = (u16*)(Lds + W2S_OFF);
    u16* WT   = (u16*)(Lds + WT_OFF);
    u16* WPS  = (u16*)(Lds + WPS_OFF);
    u16* INVP = (u16*)(Lds + INVP_OFF);

    const int t = threadIdx.x, lane = t & 63, wave = t >> 6;
    const int ln = lane & 15, lk = lane >> 4;
    const int blk = blockIdx.x;
    const int b = blk >> 6, tile = blk & 63;
    const int ty0 = (tile >> 3) * 8, tx0 = (tile & 7) * 8;

    // ---- 1) stage XP: halo 14x14, all 256 channels, fp32 -> bf16
    const float* xb = x + (size_t)b * 256 * 4096;
    for (int s = t; s < 8192; s += 512) {
        const int co = s >> 8, sp = s & 255;       // co = channel octet 0..31
        if (sp < 196) {
            const int sy = sp / 14, sx = sp - sy * 14;
            const int gy = ty0 + sy - 3, gx = tx0 + sx - 3;
            uint4 v = {0u, 0u, 0u, 0u};
            if ((unsigned)gy < 64u && (unsigned)gx < 64u) {
                const float* xp = xb + (size_t)(co * 8) * 4096 + gy * 64 + gx;
                float f[8];
#pragma unroll
                for (int j = 0; j < 8; ++j) f[j] = xp[(size_t)j * 4096];
                v.x = pk(f[0], f[1]); v.y = pk(f[2], f[3]);
                v.z = pk(f[4], f[5]); v.w = pk(f[6], f[7]);
            }
            *reinterpret_cast<uint4*>(&XP[sp * 264 + co * 8]) = v;
        }
    }
    __syncthreads();

    // ---- 2) y-GEMM: mt = wave>>1 (m-tile), nt = (wave&1)*2 + j
    {
        const int mt = wave >> 1;
        const int ym = mt * 16 + ln;               // y-channel (B-operand col)
        const float ysc = gamma[ym] * rsqrtf(var[ym] + 1e-5f);
        f32x4 yacc[2];
#pragma unroll
        for (int j = 0; j < 2; ++j)
#pragma unroll
            for (int e = 0; e < 4; ++e) yacc[j][e] = 0.f;

        for (int ks = 0; ks < 8; ++ks) {
            // B-frag: w1[ym][ks*32 + lk*8 ..+8] * ysc  (contiguous 8 floats)
            const float4 wa = *reinterpret_cast<const float4*>(
                &w1[(size_t)ym * 256 + ks * 32 + lk * 8]);
            const float4 wb = *reinterpret_cast<const float4*>(
                &w1[(size_t)ym * 256 + ks * 32 + lk * 8 + 4]);
            uint4 q;
            q.x = pk(wa.x * ysc, wa.y * ysc); q.y = pk(wa.z * ysc, wa.w * ysc);
            q.z = pk(wb.x * ysc, wb.y * ysc); q.w = pk(wb.z * ysc, wb.w * ysc);
            const bf16x8 bw = __builtin_bit_cast(bf16x8, q);
#pragma unroll
            for (int j = 0; j < 2; ++j) {
                const int nt = (wave & 1) * 2 + j;
                const int px = nt * 16 + ln;
                const int sp = ((px >> 3) + 3) * 14 + (px & 7) + 3;
                const bf16x8 a = *reinterpret_cast<const bf16x8*>(
                    &XP[sp * 264 + (ks * 4 + lk) * 8]);
                yacc[j] = __builtin_amdgcn_mfma_f32_16x16x32_bf16(a, bw, yacc[j], 0, 0, 0);
            }
        }
        // epilogue: bias + relu -> Y (k-packed by y-channel, px ^kg swizzle)
        const float ybv = beta[ym] - mean[ym] * ysc;
        const int ykg = ym >> 3, yj = ym & 7;
#pragma unroll
        for (int j = 0; j < 2; ++j) {
            const int nt = (wave & 1) * 2 + j;
#pragma unroll
            for (int r = 0; r < 4; ++r) {
                const int px = nt * 16 + lk * 4 + r;
                Y[((ykg * 64) + (px ^ ykg)) * 8 + yj] =
                    f2bf(fmaxf(yacc[j][r] + ybv, 0.f));
            }
        }
    }
    __syncthreads();

    // persistent output accumulators: oacc[n-tile 0..3][m-tile f]
    f32x4 oacc[4][2];
#pragma unroll
    for (int i = 0; i < 4; ++i)
#pragma unroll
        for (int f = 0; f < 2; ++f)
#pragma unroll
            for (int e = 0; e < 4; ++e) oacc[i][f][e] = 0.f;

    // ---- 3) group-pair loop
    for (int p = 0; p < 8; ++p) {
        const int cb = p * 32;

        // stage W2S: 112 kkp x 64k (two groups, 49+7pad each), fp32 -> bf16
        for (int s = t; s < 896; s += 512) {
            const int kkp = s >> 3, kg = s & 7;
            const int grp = (kkp >= 56) ? 1 : 0;
            const int kk = kkp - grp * 56;
            uint4 v = {0u, 0u, 0u, 0u};
            if (kk < 49) {
                const float* wr = &w2[(size_t)((2 * p + grp) * 49 + kk) * 64 + kg * 8];
                const float4 a0 = *reinterpret_cast<const float4*>(wr);
                const float4 a1 = *reinterpret_cast<const float4*>(wr + 4);
                v.x = pk(a0.x, a0.y); v.y = pk(a0.z, a0.w);
                v.z = pk(a1.x, a1.y); v.w = pk(a1.z, a1.w);
            }
            *reinterpret_cast<uint4*>(&W2S[((kg * 112) + (kkp ^ kg)) * 8]) = v;
        }
        // stage WPS: wp[m][cb + kg*8 ..+8], m fast for coalescing
        for (int s = t; s < 1024; s += 512) {
            const int m = s >> 2, kg = s & 3;
            const float* wr = &wp[(size_t)m * 256 + cb + kg * 8];
            const float4 a0 = *reinterpret_cast<const float4*>(wr);
            const float4 a1 = *reinterpret_cast<const float4*>(wr + 4);
            uint4 v;
            v.x = pk(a0.x, a0.y); v.y = pk(a0.z, a0.w);
            v.z = pk(a1.x, a1.y); v.w = pk(a1.z, a1.w);
            *reinterpret_cast<uint4*>(&WPS[((kg * 256) + (m ^ (kg << 1))) * 8]) = v;
        }
        __syncthreads();   // b1

        // wt-GEMM: 28 tiles (4 nt x 7 mt2)
#pragma unroll
        for (int s4 = 0; s4 < 4; ++s4) {
            const int tid = wave + s4 * 8;
            if (tid < 28) {
                const int nt = tid & 3, mt2 = tid >> 2;
                f32x4 wacc;
#pragma unroll
                for (int e = 0; e < 4; ++e) wacc[e] = 0.f;
#pragma unroll
                for (int k32 = 0; k32 < 2; ++k32) {
                    const int kg = k32 * 4 + lk;
                    const bf16x8 af = *reinterpret_cast<const bf16x8*>(
                        &Y[((kg * 64) + ((nt * 16 + ln) ^ kg)) * 8]);
                    const bf16x8 bf_ = *reinterpret_cast<const bf16x8*>(
                        &W2S[((kg * 112) + ((mt2 * 16 + ln) ^ kg)) * 8]);
                    wacc = __builtin_amdgcn_mfma_f32_16x16x32_bf16(af, bf_, wacc, 0, 0, 0);
                }
                const int kkp = mt2 * 16 + ln;
                const int grp = (kkp >= 56) ? 1 : 0;
                const int kk = kkp - grp * 56;
                if (kk < 49) {
                    const float bv = b2[(2 * p + grp) * 49 + kk];
                    uint2 v;
                    v.x = (u32)f2h(wacc[0] + bv) | ((u32)f2h(wacc[1] + bv) << 16);
                    v.y = (u32)f2h(wacc[2] + bv) | ((u32)f2h(wacc[3] + bv) << 16);
                    *reinterpret_cast<uint2*>(&WT[kkp * 68 + nt * 16 + lk * 4]) = v;
                }
            }
        }
        __syncthreads();   // b2

        // involution: thread = (px = lane, cq = wave); 4 channels cb+cq*4..+3
        {
            const int px = lane, cq = wave;
            const int grp = cq >> 2;
            const int kbase = (grp * 56) * 68;
            const int choff = cb + cq * 4;
            const int py = px >> 3, pxx = px & 7;
            float o0 = 0.f, o1 = 0.f, o2 = 0.f, o3 = 0.f;
            for (int dy = 0; dy < 7; ++dy) {
                const int spb = (py + dy) * 14 + pxx;
#pragma unroll
                for (int dx = 0; dx < 7; ++dx) {
                    const int kkl = dy * 7 + dx;
                    const float wv = h2f(WT[kbase + kkl * 68 + px]);
                    const uint2 u = *reinterpret_cast<const uint2*>(
                        &XP[(spb + dx) * 264 + choff]);
                    o0 += wv * bf2f((u16)(u.x & 0xffffu));
                    o1 += wv * bf2f((u16)(u.x >> 16));
                    o2 += wv * bf2f((u16)(u.y & 0xffffu));
                    o3 += wv * bf2f((u16)(u.y >> 16));
                }
            }
            const int kgl = cq >> 1, jo = (cq & 1) * 4;
            uint2 v;
            v.x = pk(o0, o1);
            v.y = pk(o2, o3);
            *reinterpret_cast<uint2*>(
                &INVP[((kgl * 64) + (px ^ (kgl << 1))) * 8 + jo]) = v;
        }
        __syncthreads();   // b3

        // final-GEMM accumulate: K=32 (this pair's channels)
#pragma unroll
        for (int f = 0; f < 2; ++f) {
            const int m = (wave * 2 + f) * 16 + ln;
            const bf16x8 bw = *reinterpret_cast<const bf16x8*>(
                &WPS[((lk * 256) + (m ^ (lk << 1))) * 8]);
#pragma unroll
            for (int i = 0; i < 4; ++i) {
                const bf16x8 a = *reinterpret_cast<const bf16x8*>(
                    &INVP[((lk * 64) + ((i * 16 + ln) ^ (lk << 1))) * 8]);
                oacc[i][f] = __builtin_amdgcn_mfma_f32_16x16x32_bf16(a, bw, oacc[i][f], 0, 0, 0);
            }
        }
        __syncthreads();   // b4
    }

    // ---- 4) epilogue: out[b][m][pix] fp32
#pragma unroll
    for (int f = 0; f < 2; ++f) {
        const int m = (wave * 2 + f) * 16 + ln;
#pragma unroll
        for (int i = 0; i < 4; ++i) {
            const int px0 = i * 16 + lk * 4;
            const int py = px0 >> 3, pxx = px0 & 7;
            float4 v = {oacc[i][f][0], oacc[i][f][1], oacc[i][f][2], oacc[i][f][3]};
            *reinterpret_cast<float4*>(
                &out[((size_t)(b * 256 + m)) * 4096 + (ty0 + py) * 64 + tx0 + pxx]) = v;
        }
    }
}

// ---------------------------------------------------------------------------
extern "C" void kernel_launch(void* const* d_in, const int* in_sizes, int n_in,
                              void* d_out, int out_size, void* d_ws, size_t ws_size,
                              hipStream_t stream)
{
    const float* x     = (const float*)d_in[0];
    const float* w1    = (const float*)d_in[1];
    const float* gamma = (const float*)d_in[2];
    const float* beta  = (const float*)d_in[3];
    const float* mean  = (const float*)d_in[4];
    const float* var   = (const float*)d_in[5];
    const float* w2    = (const float*)d_in[6];
    const float* b2    = (const float*)d_in[7];
    const float* wp    = (const float*)d_in[8];
    float* out = (float*)d_out;

    // allow >64 KiB dynamic LDS (160 KiB/CU on gfx950)
    (void)hipFuncSetAttribute((const void*)mega_k,
                              hipFuncAttributeMaxDynamicSharedMemorySize,
                              (int)LDS_SZ);
    mega_k<<<dim3(256), dim3(512), LDS_SZ, stream>>>(
        x, w1, gamma, beta, mean, var, w2, b2, wp, out);
}

// Round 13
// 48.840 us; speedup vs baseline: 4.5025x; 1.4341x over previous
//
#include <hip/hip_runtime.h>

typedef __attribute__((ext_vector_type(8))) short bf16x8;
typedef __attribute__((ext_vector_type(4))) float f32x4;
typedef __attribute__((ext_vector_type(8))) _Float16 h16x8;
typedef unsigned short u16;
typedef unsigned int u32;

__device__ __forceinline__ u16 f2bf(float f) {
    u32 x = __builtin_bit_cast(u32, f);
    return (u16)((x + 0x7fffu + ((x >> 16) & 1u)) >> 16);
}
__device__ __forceinline__ u16 f2h(float f) {
    _Float16 h = (_Float16)f;
    return __builtin_bit_cast(u16, h);
}

// ---------------------------------------------------------------------------
// Stage 1 MFMA GEMM (swapped roles): y[m][n] = relu(sum_k w1bn[m][k]*x[k][n]).
// K=256, M=64, 64n per block, 512 threads = 8 waves (wm 0..3 m-tile, wn 0..1
// n-pair). D rows = m -> each lane holds 4 consecutive m of one kg-group =>
// ypk written as coalesced uint2 (no scalar stores).
// ypk layout: [b][kg=8][4096n][8j] bf16.
// ---------------------------------------------------------------------------
__global__ __launch_bounds__(512) void gemm1m_k(
    const float* __restrict__ x,
    const float* __restrict__ w1, const float* __restrict__ gamma,
    const float* __restrict__ beta, const float* __restrict__ mean,
    const float* __restrict__ var,
    u16* __restrict__ ypk)
{
    __shared__ u16 Ws[32 * 64 * 8];    // [kg32][m64 swz][8], 32 KB
    __shared__ u16 As[2][8 * 64 * 8];  // [kg8][n64 swz][8], 2 x 8 KB

    const int t = threadIdx.x, lane = t & 63, wave = t >> 6;
    const int b = blockIdx.y, n0 = blockIdx.x * 64;
    const int ln = lane & 15, lk = lane >> 4;
    const int wm = wave >> 1, wn = wave & 1;
    const float* xb = x + (size_t)b * 256 * 4096;

    // stage BN-folded w1 -> bf16 k-packed, m XOR-swizzled by kg&7
    for (int s = t; s < 2048; s += 512) {
        int kg = s >> 6, m = s & 63;
        float sc = gamma[m] * rsqrtf(var[m] + 1e-5f);
        const float4 f0 = *reinterpret_cast<const float4*>(&w1[(size_t)m * 256 + kg * 8]);
        const float4 f1 = *reinterpret_cast<const float4*>(&w1[(size_t)m * 256 + kg * 8 + 4]);
        uint4 v;
        v.x = (u32)f2bf(f0.x * sc) | ((u32)f2bf(f0.y * sc) << 16);
        v.y = (u32)f2bf(f0.z * sc) | ((u32)f2bf(f0.w * sc) << 16);
        v.z = (u32)f2bf(f1.x * sc) | ((u32)f2bf(f1.y * sc) << 16);
        v.w = (u32)f2bf(f1.z * sc) | ((u32)f2bf(f1.w * sc) << 16);
        *reinterpret_cast<uint4*>(&Ws[((kg * 64) + (m ^ (kg & 7))) * 8]) = v;
    }

    const int skg = t >> 6, snn = t & 63;   // staging: wave=kg-slice, lane=n
    float rx[8];
#pragma unroll
    for (int j = 0; j < 8; ++j)
        rx[j] = xb[(size_t)(skg * 8 + j) * 4096 + n0 + snn];
    {
        uint4 v;
        v.x = (u32)f2bf(rx[0]) | ((u32)f2bf(rx[1]) << 16);
        v.y = (u32)f2bf(rx[2]) | ((u32)f2bf(rx[3]) << 16);
        v.z = (u32)f2bf(rx[4]) | ((u32)f2bf(rx[5]) << 16);
        v.w = (u32)f2bf(rx[6]) | ((u32)f2bf(rx[7]) << 16);
        *reinterpret_cast<uint4*>(&As[0][((skg * 64) + (snn ^ skg)) * 8]) = v;
    }
    __syncthreads();

    f32x4 acc[2];
#pragma unroll
    for (int i = 0; i < 2; ++i)
#pragma unroll
        for (int e = 0; e < 4; ++e) acc[i][e] = 0.f;

    for (int ks = 0; ks < 4; ++ks) {
        const int cur = ks & 1;
        if (ks < 3) {
#pragma unroll
            for (int j = 0; j < 8; ++j)
                rx[j] = xb[(size_t)((ks + 1) * 64 + skg * 8 + j) * 4096 + n0 + snn];
        }
#pragma unroll
        for (int k32 = 0; k32 < 2; ++k32) {
            const int kgl = k32 * 4 + lk;
            const int kgw = ks * 8 + kgl;
            // A-frag: w1 rows m
            const bf16x8 aw = *reinterpret_cast<const bf16x8*>(
                &Ws[((kgw * 64) + ((wm * 16 + ln) ^ (kgw & 7))) * 8]);
            // B-frags: x cols n
#pragma unroll
            for (int i = 0; i < 2; ++i) {
                const int n = wn * 32 + i * 16 + ln;
                const bf16x8 bx = *reinterpret_cast<const bf16x8*>(
                    &As[cur][((kgl * 64) + (n ^ kgl)) * 8]);
                acc[i] = __builtin_amdgcn_mfma_f32_16x16x32_bf16(aw, bx, acc[i], 0, 0, 0);
            }
        }
        if (ks < 3) {
            uint4 v;
            v.x = (u32)f2bf(rx[0]) | ((u32)f2bf(rx[1]) << 16);
            v.y = (u32)f2bf(rx[2]) | ((u32)f2bf(rx[3]) << 16);
            v.z = (u32)f2bf(rx[4]) | ((u32)f2bf(rx[5]) << 16);
            v.w = (u32)f2bf(rx[6]) | ((u32)f2bf(rx[7]) << 16);
            *reinterpret_cast<uint4*>(&As[cur ^ 1][((skg * 64) + (snn ^ skg)) * 8]) = v;
            __syncthreads();
        }
    }

    // epilogue: lane holds rows m = wm*16 + lk*4 + r (r=0..3), col n = ln.
    const int mb = wm * 16 + lk * 4;
    const float4 g4 = *reinterpret_cast<const float4*>(&gamma[mb]);
    const float4 v4 = *reinterpret_cast<const float4*>(&var[mb]);
    const float4 be4 = *reinterpret_cast<const float4*>(&beta[mb]);
    const float4 mn4 = *reinterpret_cast<const float4*>(&mean[mb]);
    float bv[4];
    bv[0] = be4.x - mn4.x * (g4.x * rsqrtf(v4.x + 1e-5f));
    bv[1] = be4.y - mn4.y * (g4.y * rsqrtf(v4.y + 1e-5f));
    bv[2] = be4.z - mn4.z * (g4.z * rsqrtf(v4.z + 1e-5f));
    bv[3] = be4.w - mn4.w * (g4.w * rsqrtf(v4.w + 1e-5f));
    const int kg = mb >> 3, joff = mb & 7;   // joff in {0,4}
#pragma unroll
    for (int i = 0; i < 2; ++i) {
        const int n = n0 + wn * 32 + i * 16 + ln;
        u16 p[4];
#pragma unroll
        for (int r = 0; r < 4; ++r)
            p[r] = f2bf(fmaxf(acc[i][r] + bv[r], 0.f));
        uint2 v;
        v.x = (u32)p[0] | ((u32)p[1] << 16);
        v.y = (u32)p[2] | ((u32)p[3] << 16);
        *reinterpret_cast<uint2*>(
            &ypk[(((size_t)b * 8 + kg) * 4096 + n) * 8 + joff]) = v;
    }
}

// ---------------------------------------------------------------------------
// Fused weight-gen + involution. Block = (16x16 tile, group, batch), 512 th.
// Phase 1 (MFMA, 8 waves = 4 kk-quarters x 2 px-halves):
//   wt[256px][49kk] = y[256px][64k] @ w2g[64k][49kk] + b2 -> LDS f16.
// Phase 2 (VALU, thread = (px, ch-half)): out[px][8ch] = sum_kk wt*xs.
// ---------------------------------------------------------------------------
__global__ __launch_bounds__(512, 4) void fusedinv_k(
    const u16* __restrict__ ypk, const float* __restrict__ w2,
    const float* __restrict__ b2, const float* __restrict__ x,
    u16* __restrict__ invpk)
{
    __shared__ alignas(16) char Lds[66560];
    u16* As = (u16*)Lds;                   // phase1: [8kg][256px swz][8], 32 KB
    u16* Ws = (u16*)(Lds + 32768);         // phase1: [8kg][64kk swz][8], 8 KB
    _Float16* xs = (_Float16*)Lds;         // phase2: [2][484][8] f16, 15.5 KB
    u16* wt16 = (u16*)(Lds + 40960);       // [49][260] f16, 25.5 KB

    const int t = threadIdx.x, lane = t & 63, wave = t >> 6;
    const int tile = blockIdx.x, g = blockIdx.y, b = blockIdx.z;
    const int ty0 = (tile >> 2) * 16, tx0 = (tile & 3) * 16;
    const int ln = lane & 15, lk = lane >> 4;
    const int q = wave >> 1, h = wave & 1;

    // ---- phase 1 staging: y tile (XOR-swizzled) + w2 group slice
    const u16* yb = ypk + (size_t)b * 8 * 4096 * 8;
#pragma unroll
    for (int r = 0; r < 4; ++r) {
        int s = r * 512 + t;               // s = kg*256 + n
        int kg = s >> 8, n = s & 255;
        int gpix = (ty0 + (n >> 4)) * 64 + tx0 + (n & 15);
        *reinterpret_cast<uint4*>(&As[((kg * 256) + (n ^ kg)) * 8]) =
            *reinterpret_cast<const uint4*>(&yb[((size_t)kg * 4096 + gpix) * 8]);
    }
    {
        int kg = t >> 6, m = t & 63;
        uint4 v = {0u, 0u, 0u, 0u};
        if (m < 49) {
            const float4 f0 = *reinterpret_cast<const float4*>(
                &w2[(size_t)(g * 49 + m) * 64 + kg * 8]);
            const float4 f1 = *reinterpret_cast<const float4*>(
                &w2[(size_t)(g * 49 + m) * 64 + kg * 8 + 4]);
            v.x = (u32)f2bf(f0.x) | ((u32)f2bf(f0.y) << 16);
            v.y = (u32)f2bf(f0.z) | ((u32)f2bf(f0.w) << 16);
            v.z = (u32)f2bf(f1.x) | ((u32)f2bf(f1.y) << 16);
            v.w = (u32)f2bf(f1.z) | ((u32)f2bf(f1.w) << 16);
        }
        *reinterpret_cast<uint4*>(&Ws[((kg * 64) + (m ^ kg)) * 8]) = v;
    }
    __syncthreads();

    // ---- phase 1 MFMA: wave (q,h): kk-tile q, px-tiles h*8+i (i=0..7)
    f32x4 acc[8];
#pragma unroll
    for (int i = 0; i < 8; ++i)
#pragma unroll
        for (int e = 0; e < 4; ++e) acc[i][e] = 0.f;

#pragma unroll
    for (int k32 = 0; k32 < 2; ++k32) {
        const int kg = k32 * 4 + lk;
        const bf16x8 wf = *reinterpret_cast<const bf16x8*>(
            &Ws[((kg * 64) + ((q * 16 + ln) ^ kg)) * 8]);
#pragma unroll
        for (int i = 0; i < 8; ++i) {
            const int n = (h * 8 + i) * 16 + ln;
            const bf16x8 af = *reinterpret_cast<const bf16x8*>(
                &As[((kg * 256) + (n ^ kg)) * 8]);
            acc[i] = __builtin_amdgcn_mfma_f32_16x16x32_bf16(af, wf, acc[i], 0, 0, 0);
        }
    }
    __syncthreads();   // As/Ws reads done; region reusable for xs

    // ---- epilogue: wt -> LDS f16 (col kk = q*16+ln, rows px)
    const int kk = q * 16 + ln;
    if (kk < 49) {
        const float bv = b2[g * 49 + kk];
#pragma unroll
        for (int i = 0; i < 8; ++i) {
            u16 h0 = f2h(acc[i][0] + bv), h1 = f2h(acc[i][1] + bv);
            u16 h2 = f2h(acc[i][2] + bv), h3 = f2h(acc[i][3] + bv);
            uint2 v;
            v.x = (u32)h0 | ((u32)h1 << 16);
            v.y = (u32)h2 | ((u32)h3 << 16);
            *reinterpret_cast<uint2*>(&wt16[kk * 260 + (h * 8 + i) * 16 + lk * 4]) = v;
        }
    }

    // ---- x patch staging: fp32 -> f16, 2 planes of 8 ch
    const float* xb = x + (size_t)(b * 256 + g * 16) * 4096;
    for (int idx = t; idx < 968; idx += 512) {
        int plane = idx / 484, sp = idx - plane * 484;
        int sy = sp / 22, sx = sp - sy * 22;
        int gy = ty0 + sy - 3, gx = tx0 + sx - 3;
        uint4 hh = {0u, 0u, 0u, 0u};
        if ((unsigned)gy < 64u && (unsigned)gx < 64u) {
            const float* xp = &xb[(size_t)(plane * 8) * 4096 + gy * 64 + gx];
            float f[8];
#pragma unroll
            for (int j = 0; j < 8; ++j) f[j] = xp[(size_t)j * 4096];
            hh.x = (u32)f2h(f[0]) | ((u32)f2h(f[1]) << 16);
            hh.y = (u32)f2h(f[2]) | ((u32)f2h(f[3]) << 16);
            hh.z = (u32)f2h(f[4]) | ((u32)f2h(f[5]) << 16);
            hh.w = (u32)f2h(f[6]) | ((u32)f2h(f[7]) << 16);
        }
        *reinterpret_cast<uint4*>(&xs[((size_t)plane * 484 + sp) * 8]) = hh;
    }
    __syncthreads();

    // ---- phase 2: involution; thread = (px, half), 8 channels
    const int px = t & 255, half = t >> 8;
    const int py = px >> 4, pxx = px & 15;
    float o[8];
#pragma unroll
    for (int i = 0; i < 8; ++i) o[i] = 0.f;

    for (int dy = 0; dy < 7; ++dy) {
        const int rowb = (py + dy) * 22 + pxx;
#pragma unroll
        for (int dx = 0; dx < 7; ++dx) {
            const int kkx = dy * 7 + dx;
            const float wf = (float)__builtin_bit_cast(_Float16, wt16[kkx * 260 + px]);
            const h16x8 xv = *reinterpret_cast<const h16x8*>(
                &xs[((size_t)half * 484 + rowb + dx) * 8]);
#pragma unroll
            for (int c = 0; c < 8; ++c)
                o[c] += wf * (float)xv[c];
        }
    }

    const int pix = (ty0 + py) * 64 + tx0 + pxx;
    u16 p[8];
#pragma unroll
    for (int j = 0; j < 8; ++j) p[j] = f2bf(o[j]);
    uint4 v;
    v.x = (u32)p[0] | ((u32)p[1] << 16);
    v.y = (u32)p[2] | ((u32)p[3] << 16);
    v.z = (u32)p[4] | ((u32)p[5] << 16);
    v.w = (u32)p[6] | ((u32)p[7] << 16);
    *reinterpret_cast<uint4*>(
        &invpk[(((size_t)b * 32 + g * 2 + half) * 4096 + pix) * 8]) = v;
}

// ---------------------------------------------------------------------------
// Final MFMA GEMM: out[n][m] = sum_k inv[n][k] * wp[m][k]; K=M=256, fp32 out.
// 512 threads = 8 waves (wn 0..3 n-quarter, wm 0..1 m-half). Block 64m x 128n.
// ---------------------------------------------------------------------------
__global__ __launch_bounds__(512, 4) void mgemm4_k(
    const u16* __restrict__ Apk,    // invpk [b][32][4096][8]
    const float* __restrict__ wp,   // [256][256] fp32
    float* __restrict__ Cout)
{
    __shared__ u16 As[2][8 * 128 * 8];  // 2 x 16 KB
    __shared__ u16 Ws[32 * 64 * 8];     // 32 KB

    const int t = threadIdx.x;
    const int lane = t & 63, wave = t >> 6;
    const int m0 = blockIdx.x * 64;
    const int batch = blockIdx.y >> 5;
    const int n0 = (blockIdx.y & 31) * 128;
    const u16* Ab = Apk + (size_t)batch * 32 * 4096 * 8;

    const int wn = wave & 3, wm = wave >> 2;
    const int ln = lane & 15, lk = lane >> 4;

    // stage wp slice -> bf16 k-packed, m XOR-swizzled
    for (int s = t; s < 2048; s += 512) {
        int kg = s >> 6, m = s & 63;
        const float4 f0 = *reinterpret_cast<const float4*>(
            &wp[(size_t)(m0 + m) * 256 + kg * 8]);
        const float4 f1 = *reinterpret_cast<const float4*>(
            &wp[(size_t)(m0 + m) * 256 + kg * 8 + 4]);
        uint4 v;
        v.x = (u32)f2bf(f0.x) | ((u32)f2bf(f0.y) << 16);
        v.y = (u32)f2bf(f0.z) | ((u32)f2bf(f0.w) << 16);
        v.z = (u32)f2bf(f1.x) | ((u32)f2bf(f1.y) << 16);
        v.w = (u32)f2bf(f1.z) | ((u32)f2bf(f1.w) << 16);
        *reinterpret_cast<uint4*>(&Ws[((size_t)kg * 64 + (m ^ (kg & 7))) * 8]) = v;
    }

    uint4 rs[2];
#pragma unroll
    for (int r = 0; r < 2; ++r) {
        int s = r * 512 + t, kg = s >> 7, nn = s & 127;
        rs[r] = *reinterpret_cast<const uint4*>(&Ab[((size_t)kg * 4096 + n0 + nn) * 8]);
    }
#pragma unroll
    for (int r = 0; r < 2; ++r) {
        int s = r * 512 + t, kg = s >> 7, nn = s & 127;
        *reinterpret_cast<uint4*>(&As[0][((size_t)kg * 128 + (nn ^ kg)) * 8]) = rs[r];
    }
    __syncthreads();

    f32x4 acc[2][2];
#pragma unroll
    for (int i = 0; i < 2; ++i)
#pragma unroll
        for (int f = 0; f < 2; ++f)
#pragma unroll
            for (int e = 0; e < 4; ++e) acc[i][f][e] = 0.f;

    for (int ks = 0; ks < 4; ++ks) {
        const int cur = ks & 1;
        if (ks < 3) {
#pragma unroll
            for (int r = 0; r < 2; ++r) {
                int s = r * 512 + t, kg = s >> 7, nn = s & 127;
                rs[r] = *reinterpret_cast<const uint4*>(
                    &Ab[(((size_t)(ks + 1) * 8 + kg) * 4096 + n0 + nn) * 8]);
            }
        }
#pragma unroll
        for (int k32 = 0; k32 < 2; ++k32) {
            const int kg = k32 * 4 + lk;
            const int kgw = ks * 8 + kg;
            bf16x8 a[2], bfr[2];
#pragma unroll
            for (int i = 0; i < 2; ++i) {
                int n = wn * 32 + i * 16 + ln;
                a[i] = *reinterpret_cast<const bf16x8*>(
                    &As[cur][((size_t)kg * 128 + (n ^ kg)) * 8]);
            }
#pragma unroll
            for (int f = 0; f < 2; ++f) {
                int m = wm * 32 + f * 16 + ln;
                bfr[f] = *reinterpret_cast<const bf16x8*>(
                    &Ws[((size_t)kgw * 64 + (m ^ (kgw & 7))) * 8]);
            }
#pragma unroll
            for (int i = 0; i < 2; ++i)
#pragma unroll
                for (int f = 0; f < 2; ++f)
                    acc[i][f] = __builtin_amdgcn_mfma_f32_16x16x32_bf16(
                        a[i], bfr[f], acc[i][f], 0, 0, 0);
        }
        if (ks < 3) {
#pragma unroll
            for (int r = 0; r < 2; ++r) {
                int s = r * 512 + t, kg = s >> 7, nn = s & 127;
                *reinterpret_cast<uint4*>(
                    &As[cur ^ 1][((size_t)kg * 128 + (nn ^ kg)) * 8]) = rs[r];
            }
            __syncthreads();
        }
    }

#pragma unroll
    for (int f = 0; f < 2; ++f) {
        const int m = m0 + wm * 32 + f * 16 + ln;
#pragma unroll
        for (int i = 0; i < 2; ++i) {
            const int n = n0 + wn * 32 + i * 16 + lk * 4;
            float4 v = {acc[i][f][0], acc[i][f][1], acc[i][f][2], acc[i][f][3]};
            *reinterpret_cast<float4*>(&Cout[((size_t)batch * 256 + m) * 4096 + n]) = v;
        }
    }
}

// ---------------------------------------------------------------------------
extern "C" void kernel_launch(void* const* d_in, const int* in_sizes, int n_in,
                              void* d_out, int out_size, void* d_ws, size_t ws_size,
                              hipStream_t stream)
{
    const float* x     = (const float*)d_in[0];
    const float* w1    = (const float*)d_in[1];
    const float* gamma = (const float*)d_in[2];
    const float* beta  = (const float*)d_in[3];
    const float* mean  = (const float*)d_in[4];
    const float* var   = (const float*)d_in[5];
    const float* w2    = (const float*)d_in[6];
    const float* b2    = (const float*)d_in[7];
    const float* wp    = (const float*)d_in[8];
    float* out = (float*)d_out;

    u16* u = (u16*)d_ws;
    u16* ypk   = u;                 // 4*8*4096*8  = 1,048,576
    u16* invpk = u + 1048576;       // 4*32*4096*8 = 4,194,304

    // y = relu(BN(w1 @ x)) -> k-packed bf16
    gemm1m_k<<<dim3(64, 4), 512, 0, stream>>>(x, w1, gamma, beta, mean, var, ypk);
    // fused: wt = w2g @ y + b2 (MFMA, in-LDS) ; inv = involution(x, wt)
    fusedinv_k<<<dim3(16, 16, 4), 512, 0, stream>>>(ypk, w2, b2, x, invpk);
    // out = wp @ inv  (K=256, M=256) -> fp32
    mgemm4_k<<<dim3(4, 128), 512, 0, stream>>>(invpk, wp, out);
}